// Round 1
// baseline (525.904 us; speedup 1.0000x reference)
//
#include <hip/hip_runtime.h>
#include <hip/hip_bf16.h>

// Problem constants (B, C, D, H, W) = (2, 128, 16, 64, 64)
#define BB 2
#define CC 128
#define NN 65536          // D*H*W = 16*64*64

// ---------------------------------------------------------------------------
// Kernel 0: zero the energy accumulator region of the workspace
// ---------------------------------------------------------------------------
__global__ void zero_kernel(float* __restrict__ p, int n) {
    int i = blockIdx.x * blockDim.x + threadIdx.x;
    if (i < n) p[i] = 0.0f;
}

// ---------------------------------------------------------------------------
// Kernel 1: Gram matrix  energy[b][i][j] = sum_n q[b][i][n] * q[b][j][n]
// Each block handles one (batch, 256-wide n-chunk); computes the full
// 128x128 partial Gram with 8x8 register tiles, atomicAdd into energy.
// Grid: 512 blocks x 256 threads. Reads x exactly once.
// ---------------------------------------------------------------------------
#define GRAM_CK   256      // n-chunk per block
#define GRAM_KS   32       // k per LDS stage (8 stages)

__global__ __launch_bounds__(256) void gram_kernel(
        const float* __restrict__ x, float* __restrict__ energy) {
    const int bid   = blockIdx.x;          // [0, 512)
    const int b     = bid >> 8;            // 256 chunks per batch
    const int chunk = bid & 255;
    const int n0    = chunk * GRAM_CK;

    const float* q = x + (size_t)b * CC * NN;

    __shared__ float tile[GRAM_KS][CC];    // [k][c], 16 KB

    const int t  = threadIdx.x;            // 0..255
    const int ti = t & 15;                 // row-group 0..15
    const int tj = t >> 4;                 // col-group 0..15
    const int lc = t >> 1;                 // load row 0..127
    const int lh = t & 1;                  // load half (16 floats each)

    float acc[8][8];
#pragma unroll
    for (int r = 0; r < 8; ++r)
#pragma unroll
        for (int s = 0; s < 8; ++s) acc[r][s] = 0.0f;

    for (int stage = 0; stage < GRAM_CK / GRAM_KS; ++stage) {
        // ---- load Q[0:128][n0+stage*32 .. +32] into tile[k][c] (transposed)
        const float* gq = q + (size_t)lc * NN + n0 + stage * GRAM_KS + lh * 16;
#pragma unroll
        for (int f = 0; f < 4; ++f) {
            float4 v = *(const float4*)(gq + f * 4);
            int kl = lh * 16 + f * 4;
            tile[kl + 0][lc] = v.x;
            tile[kl + 1][lc] = v.y;
            tile[kl + 2][lc] = v.z;
            tile[kl + 3][lc] = v.w;
        }
        __syncthreads();

        // ---- accumulate 8x8 outer products over 32 k's
#pragma unroll 4
        for (int k = 0; k < GRAM_KS; ++k) {
            const float4* rowp = (const float4*)&tile[k][0];
            float4 a0 = rowp[ti * 2], a1 = rowp[ti * 2 + 1];
            float4 b0 = rowp[tj * 2], b1 = rowp[tj * 2 + 1];
            float a8[8] = {a0.x, a0.y, a0.z, a0.w, a1.x, a1.y, a1.z, a1.w};
            float b8[8] = {b0.x, b0.y, b0.z, b0.w, b1.x, b1.y, b1.z, b1.w};
#pragma unroll
            for (int r = 0; r < 8; ++r)
#pragma unroll
                for (int s = 0; s < 8; ++s)
                    acc[r][s] += a8[r] * b8[s];
        }
        __syncthreads();
    }

    // ---- accumulate into global energy
    float* eb = energy + (size_t)b * CC * CC;
    const int i0 = ti * 8, j0 = tj * 8;
#pragma unroll
    for (int r = 0; r < 8; ++r)
#pragma unroll
        for (int s = 0; s < 8; ++s)
            atomicAdd(&eb[(i0 + r) * CC + (j0 + s)], acc[r][s]);
}

// ---------------------------------------------------------------------------
// Kernel 2: attention[b][i][j] = gamma * softmax_j( max_j(e) - e )
// One block (128 threads) per row.
// ---------------------------------------------------------------------------
__global__ __launch_bounds__(128) void softmax_kernel(
        const float* __restrict__ energy, const float* __restrict__ gamma,
        float* __restrict__ att) {
    const int row = blockIdx.x;            // [0, 256) = b*C + c
    const int j   = threadIdx.x;           // [0, 128)
    const float e = energy[row * CC + j];

    __shared__ float red[CC];

    // rowmax of e
    red[j] = e; __syncthreads();
    for (int s = 64; s > 0; s >>= 1) {
        if (j < s) red[j] = fmaxf(red[j], red[j + s]);
        __syncthreads();
    }
    const float M = red[0]; __syncthreads();

    const float v = M - e;                 // energy_new

    // rowmax of energy_new
    red[j] = v; __syncthreads();
    for (int s = 64; s > 0; s >>= 1) {
        if (j < s) red[j] = fmaxf(red[j], red[j + s]);
        __syncthreads();
    }
    const float m2 = red[0]; __syncthreads();

    const float p = __expf(v - m2);

    // row sum
    red[j] = p; __syncthreads();
    for (int s = 64; s > 0; s >>= 1) {
        if (j < s) red[j] += red[j + s];
        __syncthreads();
    }
    const float sum = red[0];

    att[row * CC + j] = gamma[0] * p / sum;   // pre-scale by gamma
}

// ---------------------------------------------------------------------------
// Kernel 3: out[b][c][n] = sum_k att'[b][c][k] * q[b][k][n] + x[b][c][n]
// (att' already scaled by gamma). c-tile = 16, each thread owns 4 n's.
// Grid: (64 n-chunks, 8 c-groups, 2 batches) x 256 threads.
// ---------------------------------------------------------------------------
__global__ __launch_bounds__(256) void av_kernel(
        const float* __restrict__ x, const float* __restrict__ att,
        float* __restrict__ out) {
    const int b  = blockIdx.z;
    const int c0 = blockIdx.y * 16;
    const int t  = threadIdx.x;
    const int n0 = blockIdx.x * 1024 + t * 4;

    __shared__ float4 att_s[16][CC / 4];   // [r][k4], 8 KB

    // stage the 16x128 attention tile
    {
        const float4* ag = (const float4*)(att + ((size_t)b * CC + c0) * CC);
        float4* s4 = (float4*)att_s;
        s4[t * 2]     = ag[t * 2];
        s4[t * 2 + 1] = ag[t * 2 + 1];
    }
    __syncthreads();

    const float* q = x + (size_t)b * CC * NN;

    float4 acc[16];
#pragma unroll
    for (int r = 0; r < 16; ++r) acc[r] = make_float4(0.f, 0.f, 0.f, 0.f);

    for (int k4 = 0; k4 < CC / 4; ++k4) {
        const float* qb = q + (size_t)(k4 * 4) * NN + n0;
        float4 q0 = *(const float4*)(qb);
        float4 q1 = *(const float4*)(qb + NN);
        float4 q2 = *(const float4*)(qb + 2 * (size_t)NN);
        float4 q3 = *(const float4*)(qb + 3 * (size_t)NN);
#pragma unroll
        for (int r = 0; r < 16; ++r) {
            float4 a = att_s[r][k4];       // LDS broadcast (free)
            acc[r].x += a.x * q0.x + a.y * q1.x + a.z * q2.x + a.w * q3.x;
            acc[r].y += a.x * q0.y + a.y * q1.y + a.z * q2.y + a.w * q3.y;
            acc[r].z += a.x * q0.z + a.y * q1.z + a.z * q2.z + a.w * q3.z;
            acc[r].w += a.x * q0.w + a.y * q1.w + a.z * q2.w + a.w * q3.w;
        }
    }

    // epilogue: add residual x, store
#pragma unroll
    for (int r = 0; r < 16; ++r) {
        const size_t off = ((size_t)b * CC + c0 + r) * NN + n0;
        float4 xv = *(const float4*)(x + off);
        float4 o;
        o.x = acc[r].x + xv.x;
        o.y = acc[r].y + xv.y;
        o.z = acc[r].z + xv.z;
        o.w = acc[r].w + xv.w;
        *(float4*)(out + off) = o;
    }
}

// ---------------------------------------------------------------------------
extern "C" void kernel_launch(void* const* d_in, const int* in_sizes, int n_in,
                              void* d_out, int out_size, void* d_ws, size_t ws_size,
                              hipStream_t stream) {
    const float* x     = (const float*)d_in[0];
    const float* gamma = (const float*)d_in[1];
    float* out = (float*)d_out;

    float* energy = (float*)d_ws;                      // B*C*C floats
    float* att    = energy + (size_t)BB * CC * CC;     // B*C*C floats

    const int esz = BB * CC * CC;                      // 32768
    zero_kernel<<<(esz + 255) / 256, 256, 0, stream>>>(energy, esz);

    gram_kernel<<<BB * (NN / GRAM_CK), 256, 0, stream>>>(x, energy);

    softmax_kernel<<<BB * CC, CC, 0, stream>>>(energy, gamma, att);

    dim3 avgrid(NN / 1024, CC / 16, BB);
    av_kernel<<<avgrid, 256, 0, stream>>>(x, att, out);
}

// Round 2
// 197.003 us; speedup vs baseline: 2.6695x; 2.6695x over previous
//
#include <hip/hip_runtime.h>
#include <hip/hip_bf16.h>
#include <stdint.h>

// Problem constants (B, C, D, H, W) = (2, 128, 16, 64, 64)
#define BB  2
#define CC  128
#define NNN 65536          // D*H*W

typedef __bf16 bf16x8 __attribute__((ext_vector_type(8)));
typedef float  f32x16 __attribute__((ext_vector_type(16)));

__device__ __forceinline__ uint16_t f2bf(float f) {
    uint32_t u = __float_as_uint(f);
    u = (u + 0x7fffu + ((u >> 16) & 1u)) >> 16;   // RNE
    return (uint16_t)u;
}

// ---------------------------------------------------------------------------
// Kernel 1: convert x (fp32, [b][c][n]) -> q_bf16 [b][c][n] and qT_bf16 [b][n][c]
// 64x64 tiles; LDS transpose via uint-packed tile (conflict-free-ish).
// ---------------------------------------------------------------------------
__global__ __launch_bounds__(256) void conv_kernel(const float* __restrict__ x,
        uint16_t* __restrict__ q, uint16_t* __restrict__ qT) {
    const int b  = blockIdx.z;
    const int c0 = blockIdx.y * 64;
    const int n0 = blockIdx.x * 64;
    const int t  = threadIdx.x;

    __shared__ uint32_t tileU[64][33];   // [c][n/2] packed pairs, padded

    const float*  xb = x + ((size_t)b * CC + c0) * NNN + n0;
    uint16_t*     qb = q + ((size_t)b * CC + c0) * NNN + n0;

#pragma unroll
    for (int p = 0; p < 4; ++p) {
        int idx = p * 256 + t;
        int r = idx >> 4, c4 = (idx & 15) * 4;          // r = c-row, c4 = n-col
        float4 v = *(const float4*)(xb + (size_t)r * NNN + c4);
        ushort4 o;
        o.x = f2bf(v.x); o.y = f2bf(v.y); o.z = f2bf(v.z); o.w = f2bf(v.w);
        *(ushort4*)(qb + (size_t)r * NNN + c4) = o;
        tileU[r][(c4 >> 1)]     = (uint32_t)o.x | ((uint32_t)o.y << 16);
        tileU[r][(c4 >> 1) + 1] = (uint32_t)o.z | ((uint32_t)o.w << 16);
    }
    __syncthreads();

    uint16_t* qTb = qT + ((size_t)b * NNN + n0) * CC + c0;
#pragma unroll
    for (int p = 0; p < 4; ++p) {
        int idx = p * 256 + t;
        int rn = idx >> 4, cc4 = (idx & 15) * 4;        // rn = n-row, cc4 = c-col
        int sh = (rn & 1) * 16, rc = rn >> 1;
        ushort4 o;
        o.x = (uint16_t)(tileU[cc4 + 0][rc] >> sh);
        o.y = (uint16_t)(tileU[cc4 + 1][rc] >> sh);
        o.z = (uint16_t)(tileU[cc4 + 2][rc] >> sh);
        o.w = (uint16_t)(tileU[cc4 + 3][rc] >> sh);
        *(ushort4*)(qTb + (size_t)rn * CC + cc4) = o;
    }
}

// ---------------------------------------------------------------------------
// Kernel 2: Gram partials via MFMA.  energy_p[bid][i][j] = sum_{n in chunk}
// q[i][n] q[j][n].  256 blocks (128 n-chunks of 512 per batch), 4 waves/block.
// LDS fragment-ordered: chunk (g = n/8 within 64-stage, c) at [g*129 + c].
// A-frag(32x32x16): m=lane&31, k=(lane>>5)*8+j  (both operands same layout).
// ---------------------------------------------------------------------------
__global__ __launch_bounds__(256) void gram_kernel(const uint16_t* __restrict__ q,
        float* __restrict__ partial) {
    const int bid = blockIdx.x;            // [0,256)
    const int b   = bid >> 7, pch = bid & 127;
    const int n0  = pch * 512;
    const int t   = threadIdx.x;
    const int w = t >> 6, l = t & 63, h = l >> 5, ln = l & 31;

    __shared__ uint4 lds[2][8 * 129];      // 2 x 16.5 KB, frag-ordered + pad

    const uint16_t* qb   = q + (size_t)b * CC * NNN;
    const int grow = t >> 3;               // staging c-subrow 0..31
    const int gg   = t & 7;                // staging k-group
    const uint16_t* gptr = qb + (size_t)grow * NNN + n0 + gg * 8;

    f32x16 acc[4];
#pragma unroll
    for (int j = 0; j < 4; ++j)
#pragma unroll
        for (int r = 0; r < 16; ++r) acc[j][r] = 0.0f;

    uint4 vv[4];
#pragma unroll
    for (int p4 = 0; p4 < 4; ++p4)
        vv[p4] = *(const uint4*)(gptr + (size_t)(32 * p4) * NNN);

    for (int st = 0; st < 8; ++st) {       // 8 stages x 64 n
        const int buf = st & 1;
#pragma unroll
        for (int p4 = 0; p4 < 4; ++p4)
            lds[buf][gg * 129 + 32 * p4 + grow] = vv[p4];
        if (st + 1 < 8) {
            const uint16_t* gp2 = gptr + (st + 1) * 64;
#pragma unroll
            for (int p4 = 0; p4 < 4; ++p4)
                vv[p4] = *(const uint4*)(gp2 + (size_t)(32 * p4) * NNN);
        }
        __syncthreads();
#pragma unroll
        for (int s = 0; s < 4; ++s) {      // 4 k-steps of 16
            bf16x8 fa = *(const bf16x8*)&lds[buf][(2 * s + h) * 129 + 32 * w + ln];
#pragma unroll
            for (int j = 0; j < 4; ++j) {
                bf16x8 fb = *(const bf16x8*)&lds[buf][(2 * s + h) * 129 + 32 * j + ln];
                acc[j] = __builtin_amdgcn_mfma_f32_32x32x16_bf16(fa, fb, acc[j], 0, 0, 0);
            }
        }
        __syncthreads();
    }

    float* pb = partial + (size_t)bid * (CC * CC);
#pragma unroll
    for (int j = 0; j < 4; ++j)
#pragma unroll
        for (int r = 0; r < 16; ++r) {
            int row = 32 * w + (r & 3) + 8 * (r >> 2) + 4 * h;  // verified C/D map
            pb[row * CC + 32 * j + ln] = acc[j][r];
        }
}

// ---------------------------------------------------------------------------
// Kernel 3: reduce 128 partials/batch -> energy row, then softmax(max-e),
// pre-scaled by gamma, emitted as bf16 att[b][c][k].
// ---------------------------------------------------------------------------
__global__ __launch_bounds__(128) void reduce_softmax_kernel(
        const float* __restrict__ partial, const float* __restrict__ gamma,
        uint16_t* __restrict__ attw) {
    const int row = blockIdx.x;            // b*128 + i
    const int b = row >> 7, i = row & 127;
    const int j = threadIdx.x;
    const float* base = partial + ((size_t)b * 128) * (CC * CC) + (size_t)i * CC + j;

    float s0 = 0, s1 = 0, s2 = 0, s3 = 0;
    for (int p = 0; p < 128; p += 4) {
        s0 += base[(size_t)(p + 0) * (CC * CC)];
        s1 += base[(size_t)(p + 1) * (CC * CC)];
        s2 += base[(size_t)(p + 2) * (CC * CC)];
        s3 += base[(size_t)(p + 3) * (CC * CC)];
    }
    const float e = (s0 + s1) + (s2 + s3);

    __shared__ float red[CC];
    red[j] = e; __syncthreads();
    for (int s = 64; s > 0; s >>= 1) { if (j < s) red[j] = fmaxf(red[j], red[j + s]); __syncthreads(); }
    const float M = red[0]; __syncthreads();
    const float v = M - e;                 // energy_new
    red[j] = v; __syncthreads();
    for (int s = 64; s > 0; s >>= 1) { if (j < s) red[j] = fmaxf(red[j], red[j + s]); __syncthreads(); }
    const float m2 = red[0]; __syncthreads();
    const float pexp = __expf(v - m2);
    red[j] = pexp; __syncthreads();
    for (int s = 64; s > 0; s >>= 1) { if (j < s) red[j] += red[j + s]; __syncthreads(); }
    const float sum = red[0];

    attw[(size_t)row * CC + j] = f2bf(gamma[0] * pexp / sum);
}

// ---------------------------------------------------------------------------
// Kernel 4: out[b][c][n] = sum_k att[c][k] * q[k][n] + x[c][n]  (att has gamma)
// Block: all 128 c x 256-n chunk. att fully in LDS (frag-ordered), qT tiles
// double-buffered, x residual prefetched to overlap the MFMA loop.
// ---------------------------------------------------------------------------
#define AV_NB 256
__global__ __launch_bounds__(256) void av_kernel(const uint16_t* __restrict__ qT,
        const uint16_t* __restrict__ attw, const float* __restrict__ x,
        float* __restrict__ out) {
    const int b     = blockIdx.y;
    const int nbase = blockIdx.x * AV_NB;
    const int t = threadIdx.x;
    const int w = t >> 6, l = t & 63, h = l >> 5, ln = l & 31;

    __shared__ uint4 attL[16 * 129];       // 33 KB
    __shared__ uint4 qTL[2][16 * 33];      // 2 x 8.25 KB

    {   // stage full att[b] (128x128 bf16), frag-ordered
        const uint16_t* ab = attw + (size_t)b * CC * CC;
#pragma unroll
        for (int p = 0; p < 8; ++p) {
            int c = p * 16 + (t >> 4), g = t & 15;
            attL[g * 129 + c] = *(const uint4*)(ab + (size_t)c * CC + g * 8);
        }
    }
    const uint16_t* qTb = qT + (size_t)b * NNN * CC;
    {   // stage qT tile it=0
#pragma unroll
        for (int p = 0; p < 2; ++p) {
            int nn = p * 16 + (t >> 4), g = t & 15;
            qTL[0][g * 33 + nn] = *(const uint4*)(qTb + (size_t)(nbase + nn) * CC + g * 8);
        }
    }

    const size_t obase0 = ((size_t)b * CC + 32 * w) * NNN + nbase + ln;
    const int iters = AV_NB / 32;

    for (int it = 0; it < iters; ++it) {
        __syncthreads();                   // qTL[it&1] staged by all
        const size_t ob = obase0 + it * 32;
        float xr[16];
#pragma unroll
        for (int r = 0; r < 16; ++r) {     // prefetch residual (overlaps MFMA)
            int row = (r & 3) + 8 * (r >> 2) + 4 * h;
            xr[r] = x[ob + (size_t)row * NNN];
        }
        uint4 sv0, sv1;
        if (it + 1 < iters) {              // prefetch next qT tile
            int g = t & 15;
            sv0 = *(const uint4*)(qTb + (size_t)(nbase + (it + 1) * 32 + (t >> 4)) * CC + g * 8);
            sv1 = *(const uint4*)(qTb + (size_t)(nbase + (it + 1) * 32 + 16 + (t >> 4)) * CC + g * 8);
        }
        f32x16 acc;
#pragma unroll
        for (int r = 0; r < 16; ++r) acc[r] = 0.0f;
        const int buf = it & 1;
#pragma unroll
        for (int s = 0; s < 8; ++s) {      // K = 128 = 8 x 16
            bf16x8 fa = *(const bf16x8*)&attL[(2 * s + h) * 129 + 32 * w + ln];
            bf16x8 fb = *(const bf16x8*)&qTL[buf][(2 * s + h) * 33 + ln];
            acc = __builtin_amdgcn_mfma_f32_32x32x16_bf16(fa, fb, acc, 0, 0, 0);
        }
        if (it + 1 < iters) {
            int g = t & 15;
            qTL[1 - buf][g * 33 + (t >> 4)]      = sv0;
            qTL[1 - buf][g * 33 + 16 + (t >> 4)] = sv1;
        }
#pragma unroll
        for (int r = 0; r < 16; ++r) {
            int row = (r & 3) + 8 * (r >> 2) + 4 * h;
            out[ob + (size_t)row * NNN] = acc[r] + xr[r];
        }
    }
}

// ---------------------------------------------------------------------------
extern "C" void kernel_launch(void* const* d_in, const int* in_sizes, int n_in,
                              void* d_out, int out_size, void* d_ws, size_t ws_size,
                              hipStream_t stream) {
    const float* x     = (const float*)d_in[0];
    const float* gamma = (const float*)d_in[1];
    float* out = (float*)d_out;

    // workspace layout (84 MB total)
    uint16_t* q       = (uint16_t*)d_ws;                       // 33.55 MB
    uint16_t* qT      = q + (size_t)BB * CC * NNN;             // 33.55 MB
    float*    partial = (float*)(qT + (size_t)BB * CC * NNN);  // 16.78 MB
    uint16_t* att     = (uint16_t*)(partial + (size_t)256 * CC * CC); // 64 KB

    conv_kernel<<<dim3(NNN / 64, CC / 64, BB), 256, 0, stream>>>(x, q, qT);
    gram_kernel<<<256, 256, 0, stream>>>(q, partial);
    reduce_softmax_kernel<<<BB * CC, CC, 0, stream>>>(partial, gamma, att);
    av_kernel<<<dim3(NNN / AV_NB, BB), 256, 0, stream>>>(qT, att, x, out);
}

// Round 3
// 158.409 us; speedup vs baseline: 3.3199x; 1.2436x over previous
//
#include <hip/hip_runtime.h>
#include <hip/hip_bf16.h>
#include <stdint.h>

// Problem constants (B, C, D, H, W) = (2, 128, 16, 64, 64)
#define BB  2
#define CC  128
#define NNN 65536          // D*H*W

typedef __bf16 bf16x8 __attribute__((ext_vector_type(8)));
typedef float  f32x16 __attribute__((ext_vector_type(16)));

__device__ __forceinline__ uint16_t f2bf(float f) {
    uint32_t u = __float_as_uint(f);
    u = (u + 0x7fffu + ((u >> 16) & 1u)) >> 16;   // RNE
    return (uint16_t)u;
}
__device__ __forceinline__ uint32_t pack2(float a, float b) {
    return (uint32_t)f2bf(a) | ((uint32_t)f2bf(b) << 16);
}

// ---------------------------------------------------------------------------
// Kernel 1 (fused convert + Gram + qT):
//   - reads x fp32 [b][c][n] for a 256-n chunk, converts to bf16 into LDS
//     (frag-ordered [n/8][c], pad 130), 4 stages of 64 n, double-buffered,
//     ONE barrier per stage
//   - MFMA 32x32x16 accumulates the full 128x128 Gram partial
//   - per stage, gathers LDS transposed and writes qT[b][n][c] bf16 with
//     fully-coalesced 256 B rows
// Grid: 512 blocks (2/CU) x 256 threads.
// ---------------------------------------------------------------------------
#define GCH  256           // n per block
#define GST  64            // n per stage
#define GPAD 130

__global__ __launch_bounds__(256) void gram_kernel(const float* __restrict__ x,
        uint16_t* __restrict__ qT, float* __restrict__ partial) {
    const int bid = blockIdx.x;            // [0,512)
    const int b   = bid >> 8, chunk = bid & 255;
    const int n0  = chunk * GCH;
    const int t   = threadIdx.x;
    const int w = t >> 6, l = t & 63, h = l >> 5, ln = l & 31;

    __shared__ uint4 lds[2][8 * GPAD];     // 2 x 16.6 KB

    const float* xb = x + (size_t)b * CC * NNN;

    // staging: thread covers (c = sc+32p, n-group sg) for p=0..3
    const int sc = t >> 3;                 // [0,32)
    const int sg = t & 7;                  // [0,8)

    f32x16 acc[4];
#pragma unroll
    for (int j = 0; j < 4; ++j)
#pragma unroll
        for (int r = 0; r < 16; ++r) acc[j][r] = 0.0f;

    float4 va[4], vb[4];
#pragma unroll
    for (int p = 0; p < 4; ++p) {
        const float* gp = xb + (size_t)(sc + 32 * p) * NNN + n0 + sg * 8;
        va[p] = *(const float4*)(gp);
        vb[p] = *(const float4*)(gp + 4);
    }

    for (int st = 0; st < 4; ++st) {
        const int buf = st & 1;
        // ---- write staged data (convert fp32 -> bf16) into LDS
#pragma unroll
        for (int p = 0; p < 4; ++p) {
            uint4 u;
            u.x = pack2(va[p].x, va[p].y);
            u.y = pack2(va[p].z, va[p].w);
            u.z = pack2(vb[p].x, vb[p].y);
            u.w = pack2(vb[p].z, vb[p].w);
            lds[buf][sg * GPAD + sc + 32 * p] = u;
        }
        // ---- prefetch next stage
        if (st < 3) {
#pragma unroll
            for (int p = 0; p < 4; ++p) {
                const float* gp = xb + (size_t)(sc + 32 * p) * NNN + n0 + (st + 1) * GST + sg * 8;
                va[p] = *(const float4*)(gp);
                vb[p] = *(const float4*)(gp + 4);
            }
        }
        __syncthreads();                   // single barrier per stage

        // ---- MFMA: 4 k-steps of 16 over this 64-n stage
#pragma unroll
        for (int s = 0; s < 4; ++s) {
            bf16x8 fa = *(const bf16x8*)&lds[buf][(2 * s + h) * GPAD + 32 * w + ln];
#pragma unroll
            for (int j = 0; j < 4; ++j) {
                bf16x8 fb = *(const bf16x8*)&lds[buf][(2 * s + h) * GPAD + 32 * j + ln];
                acc[j] = __builtin_amdgcn_mfma_f32_32x32x16_bf16(fa, fb, acc[j], 0, 0, 0);
            }
        }

        // ---- qT epilogue: gather 32 c-values for one n-row, store 64 B
        {
            const int rn = t >> 2;          // n-row within stage [0,64)
            const int cs = (t & 3) * 32;    // c segment
            const int gg = rn >> 3, sub = rn & 7;
            const uint16_t* lu = (const uint16_t*)&lds[buf][0];
            uint32_t ow[16];
#pragma unroll
            for (int k2 = 0; k2 < 16; ++k2) {
                uint32_t lo = lu[(gg * GPAD + cs + 2 * k2) * 8 + sub];
                uint32_t hi = lu[(gg * GPAD + cs + 2 * k2 + 1) * 8 + sub];
                ow[k2] = lo | (hi << 16);
            }
            uint16_t* qrow = qT + ((size_t)b * NNN + n0 + st * GST + rn) * CC + cs;
            *(uint4*)(qrow + 0)  = *(uint4*)&ow[0];
            *(uint4*)(qrow + 8)  = *(uint4*)&ow[4];
            *(uint4*)(qrow + 16) = *(uint4*)&ow[8];
            *(uint4*)(qrow + 24) = *(uint4*)&ow[12];
        }
    }

    // ---- write the 128x128 Gram partial
    float* pb = partial + (size_t)bid * (CC * CC);
#pragma unroll
    for (int j = 0; j < 4; ++j)
#pragma unroll
        for (int r = 0; r < 16; ++r) {
            int row = 32 * w + (r & 3) + 8 * (r >> 2) + 4 * h;   // verified C/D map
            pb[row * CC + 32 * j + ln] = acc[j][r];
        }
}

// ---------------------------------------------------------------------------
// Kernel 2: reduce 256 partials/batch -> energy row; softmax(max-e), gamma
// pre-scaled, emit bf16 att[b][c][k].  256 blocks x 256 threads
// (thread = (j, p-half)); 8 accumulators for memory-level parallelism.
// ---------------------------------------------------------------------------
__global__ __launch_bounds__(256) void reduce_softmax_kernel(
        const float* __restrict__ partial, const float* __restrict__ gamma,
        uint16_t* __restrict__ attw) {
    const int row = blockIdx.x;            // b*128 + i
    const int b = row >> 7, i = row & 127;
    const int t = threadIdx.x;
    const int j = t & 127, ph = t >> 7;

    const float* base = partial + ((size_t)(b * 256 + ph * 128)) * (CC * CC)
                      + (size_t)i * CC + j;
    float s0=0,s1=0,s2=0,s3=0,s4=0,s5=0,s6=0,s7=0;
    for (int p = 0; p < 128; p += 8) {
        s0 += base[(size_t)(p + 0) * (CC * CC)];
        s1 += base[(size_t)(p + 1) * (CC * CC)];
        s2 += base[(size_t)(p + 2) * (CC * CC)];
        s3 += base[(size_t)(p + 3) * (CC * CC)];
        s4 += base[(size_t)(p + 4) * (CC * CC)];
        s5 += base[(size_t)(p + 5) * (CC * CC)];
        s6 += base[(size_t)(p + 6) * (CC * CC)];
        s7 += base[(size_t)(p + 7) * (CC * CC)];
    }
    const float sp = ((s0 + s1) + (s2 + s3)) + ((s4 + s5) + (s6 + s7));

    __shared__ float red[256];
    __shared__ float m[128];
    red[t] = sp; __syncthreads();
    const float e = red[j] + red[j + 128];     // all threads compute (same per j)

    // rowmax of e
    if (ph == 0) m[j] = e;
    __syncthreads();
    for (int s = 64; s > 0; s >>= 1) {
        if (ph == 0 && j < s) m[j] = fmaxf(m[j], m[j + s]);
        __syncthreads();
    }
    const float M = m[0]; __syncthreads();
    const float v = M - e;                     // energy_new
    if (ph == 0) m[j] = v;
    __syncthreads();
    for (int s = 64; s > 0; s >>= 1) {
        if (ph == 0 && j < s) m[j] = fmaxf(m[j], m[j + s]);
        __syncthreads();
    }
    const float m2 = m[0]; __syncthreads();
    const float pexp = __expf(v - m2);
    if (ph == 0) m[j] = pexp;
    __syncthreads();
    for (int s = 64; s > 0; s >>= 1) {
        if (ph == 0 && j < s) m[j] += m[j + s];
        __syncthreads();
    }
    const float sum = m[0];

    if (ph == 0)
        attw[(size_t)row * CC + j] = f2bf(gamma[0] * pexp / sum);
}

// ---------------------------------------------------------------------------
// Kernel 3: out[b][c][n] = sum_k att[c][k] * qT[n][k] + x[c][n]
// (att already gamma-scaled). Full 128-c per block, 256-n chunk, att in LDS,
// qT tiles double-buffered, residual prefetched to overlap MFMA.
// ---------------------------------------------------------------------------
#define AV_NB 256
__global__ __launch_bounds__(256) void av_kernel(const uint16_t* __restrict__ qT,
        const uint16_t* __restrict__ attw, const float* __restrict__ x,
        float* __restrict__ out) {
    const int b     = blockIdx.y;
    const int nbase = blockIdx.x * AV_NB;
    const int t = threadIdx.x;
    const int w = t >> 6, l = t & 63, h = l >> 5, ln = l & 31;

    __shared__ uint4 attL[16 * 129];       // 33 KB
    __shared__ uint4 qTL[2][16 * 33];      // 2 x 8.25 KB

    {   // stage full att[b] (128x128 bf16), frag-ordered
        const uint16_t* ab = attw + (size_t)b * CC * CC;
#pragma unroll
        for (int p = 0; p < 8; ++p) {
            int c = p * 16 + (t >> 4), g = t & 15;
            attL[g * 129 + c] = *(const uint4*)(ab + (size_t)c * CC + g * 8);
        }
    }
    const uint16_t* qTb = qT + (size_t)b * NNN * CC;
    {   // stage qT tile it=0
#pragma unroll
        for (int p = 0; p < 2; ++p) {
            int nn = p * 16 + (t >> 4), g = t & 15;
            qTL[0][g * 33 + nn] = *(const uint4*)(qTb + (size_t)(nbase + nn) * CC + g * 8);
        }
    }

    const size_t obase0 = ((size_t)b * CC + 32 * w) * NNN + nbase + ln;
    const int iters = AV_NB / 32;

    for (int it = 0; it < iters; ++it) {
        __syncthreads();                   // staged buffer visible to all
        const size_t ob = obase0 + it * 32;
        float xr[16];
#pragma unroll
        for (int r = 0; r < 16; ++r) {     // prefetch residual (overlaps MFMA)
            int row = (r & 3) + 8 * (r >> 2) + 4 * h;
            xr[r] = x[ob + (size_t)row * NNN];
        }
        uint4 sv0, sv1;
        if (it + 1 < iters) {              // prefetch next qT tile
            int g = t & 15;
            sv0 = *(const uint4*)(qTb + (size_t)(nbase + (it + 1) * 32 + (t >> 4)) * CC + g * 8);
            sv1 = *(const uint4*)(qTb + (size_t)(nbase + (it + 1) * 32 + 16 + (t >> 4)) * CC + g * 8);
        }
        f32x16 acc;
#pragma unroll
        for (int r = 0; r < 16; ++r) acc[r] = 0.0f;
        const int buf = it & 1;
#pragma unroll
        for (int s = 0; s < 8; ++s) {      // K = 128 = 8 x 16
            bf16x8 fa = *(const bf16x8*)&attL[(2 * s + h) * 129 + 32 * w + ln];
            bf16x8 fb = *(const bf16x8*)&qTL[buf][(2 * s + h) * 33 + ln];
            acc = __builtin_amdgcn_mfma_f32_32x32x16_bf16(fa, fb, acc, 0, 0, 0);
        }
        if (it + 1 < iters) {
            int g = t & 15;
            qTL[1 - buf][g * 33 + (t >> 4)]      = sv0;
            qTL[1 - buf][g * 33 + 16 + (t >> 4)] = sv1;
        }
#pragma unroll
        for (int r = 0; r < 16; ++r) {
            int row = (r & 3) + 8 * (r >> 2) + 4 * h;
            out[ob + (size_t)row * NNN] = acc[r] + xr[r];
        }
    }
}

// ---------------------------------------------------------------------------
extern "C" void kernel_launch(void* const* d_in, const int* in_sizes, int n_in,
                              void* d_out, int out_size, void* d_ws, size_t ws_size,
                              hipStream_t stream) {
    const float* x     = (const float*)d_in[0];
    const float* gamma = (const float*)d_in[1];
    float* out = (float*)d_out;

    // workspace layout (~67.2 MB)
    uint16_t* qT      = (uint16_t*)d_ws;                              // 33.55 MB
    float*    partial = (float*)(qT + (size_t)BB * NNN * CC);         // 33.55 MB
    uint16_t* att     = (uint16_t*)(partial + (size_t)512 * CC * CC); // 64 KB

    gram_kernel<<<BB * (NNN / GCH), 256, 0, stream>>>(x, qT, partial);
    reduce_softmax_kernel<<<BB * CC, 256, 0, stream>>>(partial, gamma, att);
    av_kernel<<<dim3(NNN / AV_NB, BB), 256, 0, stream>>>(qT, att, x, out);
}

// Round 4
// 153.343 us; speedup vs baseline: 3.4296x; 1.0330x over previous
//
#include <hip/hip_runtime.h>
#include <hip/hip_bf16.h>
#include <stdint.h>

// Problem constants (B, C, D, H, W) = (2, 128, 16, 64, 64)
#define BB  2
#define CC  128
#define NNN 65536          // D*H*W

typedef __bf16 bf16x8 __attribute__((ext_vector_type(8)));
typedef float  f32x16 __attribute__((ext_vector_type(16)));

__device__ __forceinline__ uint16_t f2bf(float f) {
    uint32_t u = __float_as_uint(f);
    u = (u + 0x7fffu + ((u >> 16) & 1u)) >> 16;   // RNE
    return (uint16_t)u;
}
__device__ __forceinline__ uint32_t pack2(float a, float b) {
    return (uint32_t)f2bf(a) | ((uint32_t)f2bf(b) << 16);
}

// ---------------------------------------------------------------------------
// Kernel 1 (fused convert + Gram, NO qT):
//   reads x fp32 [b][c][n] for a 256-n chunk, converts bf16 into LDS
//   (frag-ordered [n/8][c]), 4 stages x 64 n, double-buffered LDS with
//   2-stage register prefetch, ONE barrier per stage, 16 MFMA/stage.
// Grid: 512 blocks x 256 threads (2 blocks/CU).
// ---------------------------------------------------------------------------
#define GCH  256
#define GST  64
#define GPAD 130

__global__ __launch_bounds__(256) void gram_kernel(const float* __restrict__ x,
        float* __restrict__ partial) {
    const int bid = blockIdx.x;            // [0,512)
    const int b   = bid >> 8, chunk = bid & 255;
    const int n0  = chunk * GCH;
    const int t   = threadIdx.x;
    const int w = t >> 6, l = t & 63, h = l >> 5, ln = l & 31;

    __shared__ uint4 lds[2][8 * GPAD];     // 2 x 16.6 KB

    const float* xb = x + (size_t)b * CC * NNN;
    const int sc = t >> 3;                 // c base [0,32), + 32p
    const int sg = t & 7;                  // n-oct within stage

    f32x16 acc[4];
#pragma unroll
    for (int j = 0; j < 4; ++j)
#pragma unroll
        for (int r = 0; r < 16; ++r) acc[j][r] = 0.0f;

    float4 va[2][4], vb[2][4];             // 2-stage register prefetch
#pragma unroll
    for (int s2 = 0; s2 < 2; ++s2)
#pragma unroll
        for (int p = 0; p < 4; ++p) {
            const float* gp = xb + (size_t)(sc + 32 * p) * NNN + n0 + s2 * GST + sg * 8;
            va[s2][p] = *(const float4*)(gp);
            vb[s2][p] = *(const float4*)(gp + 4);
        }

    for (int st = 0; st < 4; ++st) {
        const int set = st & 1;
#pragma unroll
        for (int p = 0; p < 4; ++p) {
            uint4 u;
            u.x = pack2(va[set][p].x, va[set][p].y);
            u.y = pack2(va[set][p].z, va[set][p].w);
            u.z = pack2(vb[set][p].x, vb[set][p].y);
            u.w = pack2(vb[set][p].z, vb[set][p].w);
            lds[set][sg * GPAD + sc + 32 * p] = u;
        }
        if (st + 2 < 4) {
#pragma unroll
            for (int p = 0; p < 4; ++p) {
                const float* gp = xb + (size_t)(sc + 32 * p) * NNN + n0 + (st + 2) * GST + sg * 8;
                va[set][p] = *(const float4*)(gp);
                vb[set][p] = *(const float4*)(gp + 4);
            }
        }
        __syncthreads();                   // single barrier per stage
#pragma unroll
        for (int s = 0; s < 4; ++s) {
            bf16x8 fa = *(const bf16x8*)&lds[set][(2 * s + h) * GPAD + 32 * w + ln];
#pragma unroll
            for (int j = 0; j < 4; ++j) {
                bf16x8 fb = *(const bf16x8*)&lds[set][(2 * s + h) * GPAD + 32 * j + ln];
                acc[j] = __builtin_amdgcn_mfma_f32_32x32x16_bf16(fa, fb, acc[j], 0, 0, 0);
            }
        }
    }

    float* pb = partial + (size_t)bid * (CC * CC);
#pragma unroll
    for (int j = 0; j < 4; ++j)
#pragma unroll
        for (int r = 0; r < 16; ++r) {
            int row = 32 * w + (r & 3) + 8 * (r >> 2) + 4 * h;   // verified C/D map
            pb[row * CC + 32 * j + ln] = acc[j][r];
        }
}

// ---------------------------------------------------------------------------
// Kernel 2: reduce 256 partials/batch -> energy row; softmax(max-e), gamma
// pre-scaled, emit bf16 att[b][c][k].
// ---------------------------------------------------------------------------
__global__ __launch_bounds__(256) void reduce_softmax_kernel(
        const float* __restrict__ partial, const float* __restrict__ gamma,
        uint16_t* __restrict__ attw) {
    const int row = blockIdx.x;            // b*128 + i
    const int b = row >> 7, i = row & 127;
    const int t = threadIdx.x;
    const int j = t & 127, ph = t >> 7;

    const float* base = partial + ((size_t)(b * 256 + ph * 128)) * (CC * CC)
                      + (size_t)i * CC + j;
    float s0=0,s1=0,s2=0,s3=0,s4=0,s5=0,s6=0,s7=0;
    for (int p = 0; p < 128; p += 8) {
        s0 += base[(size_t)(p + 0) * (CC * CC)];
        s1 += base[(size_t)(p + 1) * (CC * CC)];
        s2 += base[(size_t)(p + 2) * (CC * CC)];
        s3 += base[(size_t)(p + 3) * (CC * CC)];
        s4 += base[(size_t)(p + 4) * (CC * CC)];
        s5 += base[(size_t)(p + 5) * (CC * CC)];
        s6 += base[(size_t)(p + 6) * (CC * CC)];
        s7 += base[(size_t)(p + 7) * (CC * CC)];
    }
    const float sp = ((s0 + s1) + (s2 + s3)) + ((s4 + s5) + (s6 + s7));

    __shared__ float red[256];
    __shared__ float m[128];
    red[t] = sp; __syncthreads();
    const float e = red[j] + red[j + 128];

    if (ph == 0) m[j] = e;
    __syncthreads();
    for (int s = 64; s > 0; s >>= 1) {
        if (ph == 0 && j < s) m[j] = fmaxf(m[j], m[j + s]);
        __syncthreads();
    }
    const float M = m[0]; __syncthreads();
    const float v = M - e;
    if (ph == 0) m[j] = v;
    __syncthreads();
    for (int s = 64; s > 0; s >>= 1) {
        if (ph == 0 && j < s) m[j] = fmaxf(m[j], m[j + s]);
        __syncthreads();
    }
    const float m2 = m[0]; __syncthreads();
    const float pexp = __expf(v - m2);
    if (ph == 0) m[j] = pexp;
    __syncthreads();
    for (int s = 64; s > 0; s >>= 1) {
        if (ph == 0 && j < s) m[j] += m[j + s];
        __syncthreads();
    }
    const float sum = m[0];

    if (ph == 0)
        attw[(size_t)row * CC + j] = f2bf(gamma[0] * pexp / sum);
}

// ---------------------------------------------------------------------------
// Kernel 3: out[b][c][n] = sum_k att[c][k] * x_bf16[k][n] + x[c][n]
// In-kernel convert: x fp32 tile (128 k x 128 n) -> bf16 LDS (XOR-swizzled),
// B-frags gathered as 8x u16 (2-way banks = free). att (A-operand) staged
// frag-ordered. Residual re-read from global (L2-hot, same tile).
// Grid: (512, 2) x 256 threads, LDS = exactly 64 KB -> 2 blocks/CU.
// ---------------------------------------------------------------------------
#define AVN 128

union FB8 { uint16_t u[8]; bf16x8 v; };

__global__ __launch_bounds__(256) void av_kernel(const float* __restrict__ x,
        const uint16_t* __restrict__ attw, float* __restrict__ out) {
    const int b  = blockIdx.y;
    const int n0 = blockIdx.x * AVN;
    const int t  = threadIdx.x;
    const int w = t >> 6, l = t & 63, h = l >> 5, ln = l & 31;

    __shared__ uint4    attL[16 * 128];    // 32 KB: word [g=k/8][c]
    __shared__ uint16_t xL[128 * 128];     // 32 KB: [k][n ^ swz(k)]

    // ---- stage att[b] (128x128 bf16), frag-ordered, coalesced global reads
    {
        const uint16_t* ab = attw + (size_t)b * CC * CC;
#pragma unroll
        for (int p = 0; p < 8; ++p) {
            int c = p * 16 + (t >> 4), g = t & 15;
            attL[g * 128 + c] = *(const uint4*)(ab + (size_t)c * CC + g * 8);
        }
    }
    // ---- stage x tile -> bf16, swizzled
    {
        const int kr = t >> 1, nh = (t & 1) * 64;
        const int sw = ((kr & 8) << 2) | ((kr & 7) << 3);
        const float* xr = x + ((size_t)b * CC + kr) * NNN + n0 + nh;
#pragma unroll
        for (int i = 0; i < 8; ++i) {
            float4 a  = *(const float4*)(xr + i * 8);
            float4 bq = *(const float4*)(xr + i * 8 + 4);
            uint4 u;
            u.x = pack2(a.x, a.y);  u.y = pack2(a.z, a.w);
            u.z = pack2(bq.x, bq.y); u.w = pack2(bq.z, bq.w);
            *(uint4*)&xL[kr * 128 + ((nh + i * 8) ^ sw)] = u;
        }
    }
    __syncthreads();

    f32x16 acc[4];
#pragma unroll
    for (int jt = 0; jt < 4; ++jt)
#pragma unroll
        for (int r = 0; r < 16; ++r) acc[jt][r] = 0.0f;

#pragma unroll
    for (int s = 0; s < 8; ++s) {
        bf16x8 fa = *(const bf16x8*)&attL[(2 * s + h) * 128 + 32 * w + ln];
        const int k0 = s * 16 + h * 8;
#pragma unroll
        for (int jt = 0; jt < 4; ++jt) {
            FB8 fb;
#pragma unroll
            for (int jj = 0; jj < 8; ++jj) {
                const int k = k0 + jj;
                const int sw = ((k & 8) << 2) | ((k & 7) << 3);
                fb.u[jj] = xL[k * 128 + ((32 * jt + ln) ^ sw)];
            }
            acc[jt] = __builtin_amdgcn_mfma_f32_32x32x16_bf16(fa, fb.v, acc[jt], 0, 0, 0);
        }
    }

    // ---- epilogue: residual (L2-hot re-read) + store, coalesced
#pragma unroll
    for (int jt = 0; jt < 4; ++jt)
#pragma unroll
        for (int r = 0; r < 16; ++r) {
            int row = (r & 3) + 8 * (r >> 2) + 4 * h;
            size_t off = ((size_t)b * CC + 32 * w + row) * NNN + n0 + 32 * jt + ln;
            out[off] = acc[jt][r] + x[off];
        }
}

// ---------------------------------------------------------------------------
extern "C" void kernel_launch(void* const* d_in, const int* in_sizes, int n_in,
                              void* d_out, int out_size, void* d_ws, size_t ws_size,
                              hipStream_t stream) {
    const float* x     = (const float*)d_in[0];
    const float* gamma = (const float*)d_in[1];
    float* out = (float*)d_out;

    // workspace: partial 33.55 MB + att 64 KB
    float*    partial = (float*)d_ws;
    uint16_t* att     = (uint16_t*)(partial + (size_t)512 * CC * CC);

    gram_kernel<<<BB * (NNN / GCH), 256, 0, stream>>>(x, partial);
    reduce_softmax_kernel<<<BB * CC, 256, 0, stream>>>(partial, gamma, att);
    av_kernel<<<dim3(NNN / AVN, BB), 256, 0, stream>>>(x, att, out);
}

// Round 5
// 150.289 us; speedup vs baseline: 3.4993x; 1.0203x over previous
//
#include <hip/hip_runtime.h>
#include <hip/hip_bf16.h>
#include <stdint.h>

// Problem constants (B, C, D, H, W) = (2, 128, 16, 64, 64)
#define BB  2
#define CC  128
#define NNN 65536          // D*H*W

typedef __bf16 bf16x8 __attribute__((ext_vector_type(8)));
typedef float  f32x16 __attribute__((ext_vector_type(16)));

__device__ __forceinline__ uint16_t f2bf(float f) {
    uint32_t u = __float_as_uint(f);
    u = (u + 0x7fffu + ((u >> 16) & 1u)) >> 16;   // RNE
    return (uint16_t)u;
}
__device__ __forceinline__ uint32_t pack2(float a, float b) {
    return (uint32_t)f2bf(a) | ((uint32_t)f2bf(b) << 16);
}

// ---------------------------------------------------------------------------
// Kernel 1 (fused convert + Gram):
//   reads x fp32 [b][c][n] for a 256-n chunk, converts bf16 into LDS
//   (frag-ordered [n/8][c]), 4 stages x 64 n, double-buffered LDS with
//   2-stage register prefetch, ONE barrier per stage, 16 MFMA/stage.
// Grid: 512 blocks x 256 threads (2 blocks/CU).  (unchanged from R4)
// ---------------------------------------------------------------------------
#define GCH  256
#define GST  64
#define GPAD 130

__global__ __launch_bounds__(256) void gram_kernel(const float* __restrict__ x,
        float* __restrict__ partial) {
    const int bid = blockIdx.x;            // [0,512)
    const int b   = bid >> 8, chunk = bid & 255;
    const int n0  = chunk * GCH;
    const int t   = threadIdx.x;
    const int w = t >> 6, l = t & 63, h = l >> 5, ln = l & 31;

    __shared__ uint4 lds[2][8 * GPAD];     // 2 x 16.6 KB

    const float* xb = x + (size_t)b * CC * NNN;
    const int sc = t >> 3;                 // c base [0,32), + 32p
    const int sg = t & 7;                  // n-oct within stage

    f32x16 acc[4];
#pragma unroll
    for (int j = 0; j < 4; ++j)
#pragma unroll
        for (int r = 0; r < 16; ++r) acc[j][r] = 0.0f;

    float4 va[2][4], vb[2][4];             // 2-stage register prefetch
#pragma unroll
    for (int s2 = 0; s2 < 2; ++s2)
#pragma unroll
        for (int p = 0; p < 4; ++p) {
            const float* gp = xb + (size_t)(sc + 32 * p) * NNN + n0 + s2 * GST + sg * 8;
            va[s2][p] = *(const float4*)(gp);
            vb[s2][p] = *(const float4*)(gp + 4);
        }

    for (int st = 0; st < 4; ++st) {
        const int set = st & 1;
#pragma unroll
        for (int p = 0; p < 4; ++p) {
            uint4 u;
            u.x = pack2(va[set][p].x, va[set][p].y);
            u.y = pack2(va[set][p].z, va[set][p].w);
            u.z = pack2(vb[set][p].x, vb[set][p].y);
            u.w = pack2(vb[set][p].z, vb[set][p].w);
            lds[set][sg * GPAD + sc + 32 * p] = u;
        }
        if (st + 2 < 4) {
#pragma unroll
            for (int p = 0; p < 4; ++p) {
                const float* gp = xb + (size_t)(sc + 32 * p) * NNN + n0 + (st + 2) * GST + sg * 8;
                va[set][p] = *(const float4*)(gp);
                vb[set][p] = *(const float4*)(gp + 4);
            }
        }
        __syncthreads();                   // single barrier per stage
#pragma unroll
        for (int s = 0; s < 4; ++s) {
            bf16x8 fa = *(const bf16x8*)&lds[set][(2 * s + h) * GPAD + 32 * w + ln];
#pragma unroll
            for (int j = 0; j < 4; ++j) {
                bf16x8 fb = *(const bf16x8*)&lds[set][(2 * s + h) * GPAD + 32 * j + ln];
                acc[j] = __builtin_amdgcn_mfma_f32_32x32x16_bf16(fa, fb, acc[j], 0, 0, 0);
            }
        }
    }

    float* pb = partial + (size_t)bid * (CC * CC);
#pragma unroll
    for (int j = 0; j < 4; ++j)
#pragma unroll
        for (int r = 0; r < 16; ++r) {
            int row = 32 * w + (r & 3) + 8 * (r >> 2) + 4 * h;   // verified C/D map
            pb[row * CC + 32 * j + ln] = acc[j][r];
        }
}

// ---------------------------------------------------------------------------
// Kernel 2: reduce 256 partials/batch -> energy row; softmax(max-e), gamma
// pre-scaled, emit bf16 att[b][c][k].  (unchanged from R4)
// ---------------------------------------------------------------------------
__global__ __launch_bounds__(256) void reduce_softmax_kernel(
        const float* __restrict__ partial, const float* __restrict__ gamma,
        uint16_t* __restrict__ attw) {
    const int row = blockIdx.x;            // b*128 + i
    const int b = row >> 7, i = row & 127;
    const int t = threadIdx.x;
    const int j = t & 127, ph = t >> 7;

    const float* base = partial + ((size_t)(b * 256 + ph * 128)) * (CC * CC)
                      + (size_t)i * CC + j;
    float s0=0,s1=0,s2=0,s3=0,s4=0,s5=0,s6=0,s7=0;
    for (int p = 0; p < 128; p += 8) {
        s0 += base[(size_t)(p + 0) * (CC * CC)];
        s1 += base[(size_t)(p + 1) * (CC * CC)];
        s2 += base[(size_t)(p + 2) * (CC * CC)];
        s3 += base[(size_t)(p + 3) * (CC * CC)];
        s4 += base[(size_t)(p + 4) * (CC * CC)];
        s5 += base[(size_t)(p + 5) * (CC * CC)];
        s6 += base[(size_t)(p + 6) * (CC * CC)];
        s7 += base[(size_t)(p + 7) * (CC * CC)];
    }
    const float sp = ((s0 + s1) + (s2 + s3)) + ((s4 + s5) + (s6 + s7));

    __shared__ float red[256];
    __shared__ float m[128];
    red[t] = sp; __syncthreads();
    const float e = red[j] + red[j + 128];

    if (ph == 0) m[j] = e;
    __syncthreads();
    for (int s = 64; s > 0; s >>= 1) {
        if (ph == 0 && j < s) m[j] = fmaxf(m[j], m[j + s]);
        __syncthreads();
    }
    const float M = m[0]; __syncthreads();
    const float v = M - e;
    if (ph == 0) m[j] = v;
    __syncthreads();
    for (int s = 64; s > 0; s >>= 1) {
        if (ph == 0 && j < s) m[j] = fmaxf(m[j], m[j + s]);
        __syncthreads();
    }
    const float m2 = m[0]; __syncthreads();
    const float pexp = __expf(v - m2);
    if (ph == 0) m[j] = pexp;
    __syncthreads();
    for (int s = 64; s > 0; s >>= 1) {
        if (ph == 0 && j < s) m[j] += m[j + s];
        __syncthreads();
    }
    const float sum = m[0];

    if (ph == 0)
        attw[(size_t)row * CC + j] = f2bf(gamma[0] * pexp / sum);
}

// ---------------------------------------------------------------------------
// Kernel 3 (rebuilt): out[b][c][n] = sum_k att[c][k] * xbf[k][n] + x[c][n]
//   - stage 256n x 128c tile CHANNEL-PACKED: xT[g2=c/8][n'] uint4 = 8 consec
//     channels at one n; built via strided float4 loads + register transpose.
//     XOR swizzle n' = n ^ ((n>>2)&7): staging writes AND frag reads are
//     bank-conflict-free (each 8-lane group covers all 8 bank-quads).
//   - A-operand (att) preloaded from global into 8 reg frags (L2-resident).
//   - B-frags are single ds_read_b128 (vs R4's 8x ds_read_u16 gather).
//   - residual re-read fp32 from global (L2-hot: just staged by this block).
// Grid: 512 blocks x 256 threads, LDS = exactly 64 KB -> 2 blocks/CU.
// ---------------------------------------------------------------------------
#define AVN 256

__global__ __launch_bounds__(256, 2) void av_kernel(const float* __restrict__ x,
        const uint16_t* __restrict__ attw, float* __restrict__ out) {
    const int bid = blockIdx.x;            // [0,512)
    const int b   = bid >> 8;
    const int n0  = (bid & 255) * AVN;
    const int t   = threadIdx.x;
    const int w = t >> 6, l = t & 63, h = l >> 5, ln = l & 31;

    __shared__ uint4 xT[16 * 256];         // 64 KB: [c/8][n ^ ((n>>2)&7)]

    const float* xb = x + (size_t)b * CC * NNN;

    // ---- stage: 4 tasks/thread; task = (g2 = 4w+p, all 256 n via 64 lanes)
#pragma unroll
    for (int p = 0; p < 4; ++p) {
        const int g2 = 4 * w + p;
        float4 v[8];
#pragma unroll
        for (int j = 0; j < 8; ++j)        // 8 channel rows, lane-coalesced
            v[j] = *(const float4*)(xb + (size_t)(8 * g2 + j) * NNN + n0 + 4 * l);
#pragma unroll
        for (int i = 0; i < 4; ++i) {      // transpose in registers
            const float* f = (const float*)v;   // v[j] component i = f[4j+i]
            uint4 u;
            u.x = pack2(v[0].x * 0.f + ((const float*)&v[0])[i], ((const float*)&v[1])[i]);
            u.x = pack2(((const float*)&v[0])[i], ((const float*)&v[1])[i]);
            u.y = pack2(((const float*)&v[2])[i], ((const float*)&v[3])[i]);
            u.z = pack2(((const float*)&v[4])[i], ((const float*)&v[5])[i]);
            u.w = pack2(((const float*)&v[6])[i], ((const float*)&v[7])[i]);
            const int n  = 4 * l + i;
            const int nA = n ^ (l & 7);    // == n ^ ((n>>2)&7)
            xT[g2 * 256 + nA] = u;
            (void)f;
        }
    }

    // ---- preload A-frags (att rows for this wave's 32 channels), L2-hot
    bf16x8 fa[8];
    {
        const uint16_t* ab = attw + ((size_t)b * CC + 32 * w + ln) * CC + h * 8;
#pragma unroll
        for (int s = 0; s < 8; ++s)
            fa[s] = *(const bf16x8*)(ab + s * 16);
    }
    __syncthreads();

    // ---- main loop: 8 n-subtiles of 32
#pragma unroll
    for (int jt = 0; jt < 8; ++jt) {
        const int n  = 32 * jt + ln;
        const int nA = n ^ ((ln >> 2) & 7);

        float xr[16];                       // residual prefetch (L2-hot)
#pragma unroll
        for (int r = 0; r < 16; ++r) {
            int row = (r & 3) + 8 * (r >> 2) + 4 * h;
            xr[r] = xb[(size_t)(32 * w + row) * NNN + n0 + n];
        }

        f32x16 acc;
#pragma unroll
        for (int r = 0; r < 16; ++r) acc[r] = 0.0f;
#pragma unroll
        for (int s = 0; s < 8; ++s) {
            bf16x8 fb = *(const bf16x8*)&xT[(2 * s + h) * 256 + nA];
            acc = __builtin_amdgcn_mfma_f32_32x32x16_bf16(fa[s], fb, acc, 0, 0, 0);
        }
#pragma unroll
        for (int r = 0; r < 16; ++r) {
            int row = (r & 3) + 8 * (r >> 2) + 4 * h;
            out[((size_t)b * CC + 32 * w + row) * NNN + n0 + n] = acc[r] + xr[r];
        }
    }
}

// ---------------------------------------------------------------------------
extern "C" void kernel_launch(void* const* d_in, const int* in_sizes, int n_in,
                              void* d_out, int out_size, void* d_ws, size_t ws_size,
                              hipStream_t stream) {
    const float* x     = (const float*)d_in[0];
    const float* gamma = (const float*)d_in[1];
    float* out = (float*)d_out;

    // workspace: partial 33.55 MB + att 64 KB
    float*    partial = (float*)d_ws;
    uint16_t* att     = (uint16_t*)(partial + (size_t)512 * CC * CC);

    gram_kernel<<<BB * (NNN / GCH), 256, 0, stream>>>(x, partial);
    reduce_softmax_kernel<<<BB * CC, 256, 0, stream>>>(partial, gamma, att);
    av_kernel<<<BB * (NNN / AVN), 256, 0, stream>>>(x, att, out);
}